// Round 15
// baseline (166.679 us; speedup 1.0000x reference)
//
#include <hip/hip_runtime.h>
#include <stdint.h>

typedef __attribute__((ext_vector_type(8))) __bf16 bf16x8;
typedef __attribute__((ext_vector_type(4))) __bf16 bf16x4;
typedef __attribute__((ext_vector_type(4))) float  f32x4;

#define DEV __device__ __forceinline__

DEV void gload16(const void* g, void* l) {
  __builtin_amdgcn_global_load_lds((const __attribute__((address_space(1))) uint32_t*)g,
                                   (__attribute__((address_space(3))) uint32_t*)l,
                                   16, 0, 0);
}

DEV f32x4 mfma16(bf16x8 a, bf16x8 b, f32x4 c) {
  return __builtin_amdgcn_mfma_f32_16x16x32_bf16(a, b, c, 0, 0, 0);
}

// ---------------- workspace layout (bytes) ----------------
#define XB_OFF   0UL            // xbb: 16384 x 1024 bf16 = 33,554,432 ; reused as S (group mode)
#define S_OFF    0UL            // S (4-batch group): 33,554,432
#define Q_OFF    33554432UL     // 16384 x 512 bf16 = 16,777,216
#define K_OFF    50331648UL
#define VT_OFF   67108864UL     // [8][512][2048] bf16 = 16,777,216
#define WT_OFF   83886080UL     // 1536 x 1024 bf16 = 3,145,728
#define ENVQ_OFF 87031808UL     // 8 x 1536 f32 = 49,152
#define GATE_OFF 87080960UL     // 16384 f32 = 65,536
#define LP_OFF   87146496UL     // l_part: 16384 x 16 f32 = 2,097,152
#define INVL_OFF 89243648UL     // inv_l: 16384 f32 = 65,536
#define S8_OFF   89309184UL     // S (all 8): 67,108,864 -> needs ws >= 156,418,048

// ============ kernel 1: xbb (bf16 cast of tf) + gate ============
__global__ __launch_bounds__(256) void k_xbgate(
    const float* __restrict__ tf, const float* __restrict__ env,
    const float* __restrict__ Wg, const float* __restrict__ bg,
    __bf16* __restrict__ xbb, float* __restrict__ gate) {
  const int row = blockIdx.x;     // 0..16383
  const int t   = threadIdx.x;    // 0..255
  const int b   = row >> 11;
  const float4 v  = ((const float4*)(tf + (size_t)row * 1024))[t];
  const float4 wv = ((const float4*)Wg)[t];
  float dot = v.x * wv.x + v.y * wv.y + v.z * wv.z + v.w * wv.w;
  bf16x4 o; o.x = (__bf16)v.x; o.y = (__bf16)v.y; o.z = (__bf16)v.z; o.w = (__bf16)v.w;
  *(bf16x4*)(xbb + (size_t)row * 1024 + t * 4) = o;
  if (t < 16) {
    const float4 e  = ((const float4*)(env + b * 64))[t];
    const float4 we = ((const float4*)Wg)[256 + t];
    dot += e.x * we.x + e.y * we.y + e.z * we.z + e.w * we.w;
  }
  #pragma unroll
  for (int m = 1; m < 64; m <<= 1) dot += __shfl_xor(dot, m, 64);
  __shared__ float red[4];
  if ((t & 63) == 0) red[t >> 6] = dot;
  __syncthreads();
  if (t == 0) {
    const float d = red[0] + red[1] + red[2] + red[3] + bg[0];
    gate[row] = 0.03125f / (1.0f + __expf(-d));   // sigmoid * 1/sqrt(1024)
  }
}

// ============ kernel 2: Wt[n][kk] = W[kk][n], kk < 1024 only ============
__global__ __launch_bounds__(256) void k_wt(
    const float* __restrict__ Wq, const float* __restrict__ Wk, const float* __restrict__ Wv,
    __bf16* __restrict__ Wt) {
  __shared__ float tile[64][65];
  const int kt = blockIdx.x;       // 0..15
  const int ct = blockIdx.y;       // 0..7
  const int which = blockIdx.z;    // 0=q 1=k 2=v
  const float* W = (which == 0) ? Wq : (which == 1) ? Wk : Wv;
  const int t = threadIdx.x;
  const int k0 = kt * 64, c0 = ct * 64;
  #pragma unroll
  for (int j = 0; j < 4; ++j) {
    const int rr = (t >> 4) + j * 16;
    const float4 v4 = *(const float4*)(W + (size_t)(k0 + rr) * 512 + c0 + (t & 15) * 4);
    tile[rr][(t & 15) * 4 + 0] = v4.x;
    tile[rr][(t & 15) * 4 + 1] = v4.y;
    tile[rr][(t & 15) * 4 + 2] = v4.z;
    tile[rr][(t & 15) * 4 + 3] = v4.w;
  }
  __syncthreads();
  #pragma unroll
  for (int j = 0; j < 4; ++j) {
    const int nl = (t >> 4) + j * 16;
    const int kl = (t & 15) * 4;
    bf16x4 o;
    o.x = (__bf16)tile[kl + 0][nl];
    o.y = (__bf16)tile[kl + 1][nl];
    o.z = (__bf16)tile[kl + 2][nl];
    o.w = (__bf16)tile[kl + 3][nl];
    *(bf16x4*)(Wt + (size_t)(which * 512 + c0 + nl) * 1024 + k0 + kl) = o;
  }
}

// ============ kernel 2b: envq[b][n] = bias[n] + env[b] . W[1024:1088][col] ============
__global__ __launch_bounds__(256) void k_envq(
    const float* __restrict__ env,
    const float* __restrict__ Wq, const float* __restrict__ Wk, const float* __restrict__ Wv,
    const float* __restrict__ bq, const float* __restrict__ bk, const float* __restrict__ bv,
    float* __restrict__ envq) {
  const int n = blockIdx.x * 256 + threadIdx.x;   // 0..1535
  const int b = blockIdx.y;
  const int which = n >> 9, col = n & 511;
  const float* W    = (which == 0) ? Wq : (which == 1) ? Wk : Wv;
  const float* bias = (which == 0) ? bq : (which == 1) ? bk : bv;
  float s = bias[col];
  #pragma unroll 8
  for (int kk = 0; kk < 64; ++kk)
    s += env[b * 64 + kk] * W[(size_t)(1024 + kk) * 512 + col];
  envq[b * 1536 + n] = s;
}

// ============ kernel 3: QKV GEMM  M=16384 N=1536 K=1024 (m97 structure) ============
// (256,4): 64 VGPR + 64 acc = 128 unified exactly -> 4 blocks/CU.
__global__ __launch_bounds__(256, 4) void k_gemm(
    const __bf16* __restrict__ xbb, const __bf16* __restrict__ Wt,
    const float* __restrict__ envq, const float* __restrict__ gate,
    __bf16* __restrict__ q, __bf16* __restrict__ k, __bf16* __restrict__ vT) {
  __shared__ alignas(16) __bf16 SM[16384];   // As | Bs ; reused as transpose tile
  __bf16* As = SM;
  __bf16* Bs = SM + 8192;
  const int id = blockIdx.x;
  const int xcd = id & 7, local = id >> 3;
  const int bm = xcd * 16 + (local & 15);
  const int bn = local >> 4;
  const int tid = threadIdx.x, w = tid >> 6, lane = tid & 63;
  const int g = lane >> 4, l15 = lane & 15;
  const int wm = w >> 1, wn = w & 1;
  f32x4 acc[4][4] = {};
  const char* Ab = (const char*)(xbb + (size_t)bm * 128 * 1024);
  const char* Bb = (const char*)(Wt + (size_t)bn * 128 * 1024);

  for (int kt = 0; kt < 16; ++kt) {
    const int k0b = kt * 128;
    #pragma unroll
    for (int i = 0; i < 4; ++i) {
      const int L = i * 4096 + w * 1024 + lane * 16;
      const int row = L >> 7;
      const int ch = (L >> 4) & 7;
      const int sch = ch ^ (row & 7);
      gload16(Ab + (size_t)row * 2048 + k0b + sch * 16, (char*)As + L);
      gload16(Bb + (size_t)row * 2048 + k0b + sch * 16, (char*)Bs + L);
    }
    __syncthreads();
    #pragma unroll
    for (int kk = 0; kk < 2; ++kk) {
      bf16x8 aF[4], bF[4];
      #pragma unroll
      for (int i = 0; i < 4; ++i) {
        const int rowa = wm * 64 + i * 16 + l15;
        const int cha = (kk * 4 + g) ^ (rowa & 7);
        aF[i] = *(const bf16x8*)((const char*)As + rowa * 128 + cha * 16);
        const int rowb = wn * 64 + i * 16 + l15;
        const int chb = (kk * 4 + g) ^ (rowb & 7);
        bF[i] = *(const bf16x8*)((const char*)Bs + rowb * 128 + chb * 16);
      }
      #pragma unroll
      for (int i = 0; i < 4; ++i)
        #pragma unroll
        for (int j = 0; j < 4; ++j)
          acc[i][j] = mfma16(aF[i], bF[j], acc[i][j]);
    }
    __syncthreads();
  }

  const int which = bn >> 2;          // 0=q 1=k 2=v (block-uniform)
  const int batch = bm >> 4;          // 128-row tiles never cross batch
  if (which < 2) {
    __bf16* outp = (which == 0) ? q : k;
    const int ncolbase = bn * 128 + wn * 64 - which * 512;
    #pragma unroll
    for (int i = 0; i < 4; ++i) {
      #pragma unroll
      for (int r = 0; r < 4; ++r) {
        const int mrow = bm * 128 + wm * 64 + i * 16 + g * 4 + r;
        const float gt = (which == 0) ? gate[mrow] : 1.0f;
        #pragma unroll
        for (int j = 0; j < 4; ++j) {
          const int ncol = ncolbase + j * 16 + l15;
          float val = acc[i][j][r] + envq[batch * 1536 + bn * 128 + wn * 64 + j * 16 + l15];
          if (which == 0) val *= gt;
          outp[(size_t)mrow * 512 + ncol] = (__bf16)val;
        }
      }
    }
  } else {
    // v-block: bias add + 128x128 LDS transpose (XOR swizzle) -> vT
    #pragma unroll
    for (int j = 0; j < 4; ++j) {
      const int ncol = wn * 64 + j * 16 + l15;                 // local dim 0..127
      const float bv = envq[batch * 1536 + bn * 128 + ncol];
      const int sw = (ncol & 7) << 3;
      #pragma unroll
      for (int i = 0; i < 4; ++i) {
        const int mbase = wm * 64 + i * 16 + g * 4;            // local key, 4-aligned
        bf16x4 pk;
        pk.x = (__bf16)(acc[i][j][0] + bv);
        pk.y = (__bf16)(acc[i][j][1] + bv);
        pk.z = (__bf16)(acc[i][j][2] + bv);
        pk.w = (__bf16)(acc[i][j][3] + bv);
        *(bf16x4*)(SM + ncol * 128 + (mbase ^ sw)) = pk;
      }
    }
    __syncthreads();
    const int colL = tid & 127, h = tid >> 7;
    const __bf16* src = SM + colL * 128;
    const int sw = (colL & 7) << 3;
    __bf16* dst = vT + ((size_t)batch * 512 + (bn - 8) * 128 + colL) * 2048
                     + (bm & 15) * 128 + h * 64;
    #pragma unroll
    for (int c = 0; c < 8; ++c) {
      const int m0 = h * 64 + c * 8;
      *(bf16x8*)(dst + c * 8) = *(const bf16x8*)(src + (m0 ^ sw));
    }
  }
}

// ============ kernel 5: S = exp(Q @ K^T) + deterministic row-sum partials ============
template<int NB>
__global__ __launch_bounds__(256, 3) void k_sexp(
    const __bf16* __restrict__ q, const __bf16* __restrict__ kg,
    __bf16* __restrict__ S, float* __restrict__ l_part) {
  __shared__ alignas(16) __bf16 As[8192];
  __shared__ alignas(16) __bf16 Bs[8192];
  const int id = blockIdx.x;
  int batch, t;
  if (NB == 8) { batch = id & 7;        t = id >> 3; }
  else         { batch = (id & 7) >> 1; t = ((id >> 3) << 1) | (id & 1); }
  const int mt = t & 15, nt = t >> 4;
  const int tid = threadIdx.x, w = tid >> 6, lane = tid & 63;
  const int g = lane >> 4, l15 = lane & 15;
  const int wm = w >> 1, wn = w & 1;
  f32x4 acc[4][4] = {};
  const char* Ab = (const char*)(q  + ((size_t)batch * 2048 + mt * 128) * 512);
  const char* Bb = (const char*)(kg + ((size_t)batch * 2048 + nt * 128) * 512);

  for (int kt = 0; kt < 8; ++kt) {
    const int k0b = kt * 128;
    #pragma unroll
    for (int i = 0; i < 4; ++i) {
      const int L = i * 4096 + w * 1024 + lane * 16;
      const int row = L >> 7;
      const int ch = (L >> 4) & 7;
      const int sch = ch ^ (row & 7);
      gload16(Ab + (size_t)row * 1024 + k0b + sch * 16, (char*)As + L);
      gload16(Bb + (size_t)row * 1024 + k0b + sch * 16, (char*)Bs + L);
    }
    __syncthreads();
    #pragma unroll
    for (int kk = 0; kk < 2; ++kk) {
      bf16x8 aF[4], bF[4];
      #pragma unroll
      for (int i = 0; i < 4; ++i) {
        const int rowa = wm * 64 + i * 16 + l15;
        const int cha = (kk * 4 + g) ^ (rowa & 7);
        aF[i] = *(const bf16x8*)((const char*)As + rowa * 128 + cha * 16);
        const int rowb = wn * 64 + i * 16 + l15;
        const int chb = (kk * 4 + g) ^ (rowb & 7);
        bF[i] = *(const bf16x8*)((const char*)Bs + rowb * 128 + chb * 16);
      }
      #pragma unroll
      for (int i = 0; i < 4; ++i)
        #pragma unroll
        for (int j = 0; j < 4; ++j)
          acc[i][j] = mfma16(aF[i], bF[j], acc[i][j]);
    }
    __syncthreads();
  }

  // epilogue: S = bf16(exp(acc)); deterministic row partials over this block's cols
  __bf16* Srow = S + (size_t)batch * 2048 * 2048;
  float p[4][4];
  #pragma unroll
  for (int i = 0; i < 4; ++i) {
    #pragma unroll
    for (int r = 0; r < 4; ++r) {
      const int mrow = mt * 128 + wm * 64 + i * 16 + g * 4 + r;
      float s0 = 0.f;
      #pragma unroll
      for (int j = 0; j < 4; ++j) {
        const float e = __expf(acc[i][j][r]);
        s0 += e;
        const int ncol = nt * 128 + wn * 64 + j * 16 + l15;
        Srow[(size_t)mrow * 2048 + ncol] = (__bf16)e;
      }
      s0 += __shfl_xor(s0, 1, 64);
      s0 += __shfl_xor(s0, 2, 64);
      s0 += __shfl_xor(s0, 4, 64);
      s0 += __shfl_xor(s0, 8, 64);
      p[i][r] = s0;            // broadcast across the 16-lane group
    }
  }
  float* lx = (float*)As;      // [wm][wn][row64] = [2][2][64]
  if (l15 == 0) {
    #pragma unroll
    for (int i = 0; i < 4; ++i)
      #pragma unroll
      for (int r = 0; r < 4; ++r)
        lx[(wm * 2 + wn) * 64 + i * 16 + g * 4 + r] = p[i][r];
  }
  __syncthreads();
  if (wn == 0) {
    const int row64 = lane;    // 0..63
    const float v = lx[(wm * 2 + 0) * 64 + row64] + lx[(wm * 2 + 1) * 64 + row64];
    l_part[((size_t)batch * 2048 + mt * 128 + wm * 64 + row64) * 16 + nt] = v;
  }
}

// ============ kernel 5b: inv_l[row] = 1 / sum(l_part[row][0..15]) ============
__global__ __launch_bounds__(256) void k_lred(const float* __restrict__ l_part,
                                              float* __restrict__ inv_l) {
  const int row = blockIdx.x * 256 + threadIdx.x;
  const float4* lp = (const float4*)(l_part + (size_t)row * 16);
  const float4 a = lp[0], b = lp[1], c = lp[2], d = lp[3];
  const float s = ((a.x + a.y) + (a.z + a.w)) + ((b.x + b.y) + (b.z + b.w))
                + ((c.x + c.y) + (c.z + c.w)) + ((d.x + d.y) + (d.z + d.w));
  inv_l[row] = 1.0f / s;
}

// ============ kernel 6: out = (S @ vT-rows) * inv_l, m97 128^2 tile ============
template<int NB>
__global__ __launch_bounds__(256, 3) void k_pv(
    const __bf16* __restrict__ S, const __bf16* __restrict__ vT,
    const float* __restrict__ inv_l, float* __restrict__ out) {
  __shared__ alignas(16) __bf16 As[8192];
  __shared__ alignas(16) __bf16 Bs[8192];
  const int id = blockIdx.x;
  int batch, mt, nt;
  if (NB == 8) { batch = id & 7; const int h = id >> 3; mt = h & 15; nt = h >> 4; }
  else { batch = (id & 7) >> 1; const int h = ((id >> 3) << 1) | (id & 1); mt = h & 15; nt = h >> 4; }
  const int tid = threadIdx.x, w = tid >> 6, lane = tid & 63;
  const int g = lane >> 4, l15 = lane & 15;
  const int wm = w >> 1, wn = w & 1;
  f32x4 acc[4][4] = {};

  const char* Ab = (const char*)(S  + ((size_t)batch * 2048 + mt * 128) * 2048);
  const char* Bb = (const char*)(vT + ((size_t)batch * 512 + nt * 128) * 2048);

  for (int kt = 0; kt < 32; ++kt) {
    const int k0b = kt * 128;
    #pragma unroll
    for (int i = 0; i < 4; ++i) {
      const int L = i * 4096 + w * 1024 + lane * 16;
      const int row = L >> 7, ch = (L >> 4) & 7, sch = ch ^ (row & 7);
      gload16(Ab + (size_t)row * 4096 + k0b + sch * 16, (char*)As + L);
      gload16(Bb + (size_t)row * 4096 + k0b + sch * 16, (char*)Bs + L);
    }
    __syncthreads();
    #pragma unroll
    for (int kk = 0; kk < 2; ++kk) {
      bf16x8 aF[4], bF[4];
      #pragma unroll
      for (int i = 0; i < 4; ++i) {
        const int rowa = wm * 64 + i * 16 + l15;
        const int cha = (kk * 4 + g) ^ (rowa & 7);
        aF[i] = *(const bf16x8*)((const char*)As + rowa * 128 + cha * 16);
        const int rowb = wn * 64 + i * 16 + l15;
        const int chb = (kk * 4 + g) ^ (rowb & 7);
        bF[i] = *(const bf16x8*)((const char*)Bs + rowb * 128 + chb * 16);
      }
      #pragma unroll
      for (int i = 0; i < 4; ++i)
        #pragma unroll
        for (int j = 0; j < 4; ++j)
          acc[i][j] = mfma16(aF[i], bF[j], acc[i][j]);
    }
    __syncthreads();
  }

  #pragma unroll
  for (int i = 0; i < 4; ++i) {
    #pragma unroll
    for (int r = 0; r < 4; ++r) {
      const size_t mrow = (size_t)batch * 2048 + mt * 128 + wm * 64 + i * 16 + g * 4 + r;
      const float inv = inv_l[mrow];
      #pragma unroll
      for (int j = 0; j < 4; ++j) {
        const int ncol = nt * 128 + wn * 64 + j * 16 + l15;
        out[mrow * 512 + ncol] = acc[i][j][r] * inv;
      }
    }
  }
}

// ============ launcher ============
extern "C" void kernel_launch(void* const* d_in, const int* in_sizes, int n_in,
                              void* d_out, int out_size, void* d_ws, size_t ws_size,
                              hipStream_t stream) {
  const float* tf  = (const float*)d_in[0];
  const float* env = (const float*)d_in[1];
  const float* Wq  = (const float*)d_in[2];
  const float* bq  = (const float*)d_in[3];
  const float* Wk  = (const float*)d_in[4];
  const float* bk  = (const float*)d_in[5];
  const float* Wv  = (const float*)d_in[6];
  const float* bv  = (const float*)d_in[7];
  const float* Wg  = (const float*)d_in[8];
  const float* bg  = (const float*)d_in[9];
  float* out = (float*)d_out;
  char* ws = (char*)d_ws;

  __bf16* xbb  = (__bf16*)(ws + XB_OFF);
  __bf16* Sbuf = (__bf16*)(ws + S_OFF);
  __bf16* qb   = (__bf16*)(ws + Q_OFF);
  __bf16* kb   = (__bf16*)(ws + K_OFF);
  __bf16* vT   = (__bf16*)(ws + VT_OFF);
  __bf16* Wt   = (__bf16*)(ws + WT_OFF);
  float* envq  = (float*)(ws + ENVQ_OFF);
  float* gate  = (float*)(ws + GATE_OFF);
  float* lpart = (float*)(ws + LP_OFF);
  float* invl  = (float*)(ws + INVL_OFF);

  k_xbgate<<<dim3(16384), dim3(256), 0, stream>>>(tf, env, Wg, bg, xbb, gate);
  k_wt<<<dim3(16, 8, 3), dim3(256), 0, stream>>>(Wq, Wk, Wv, Wt);
  k_envq<<<dim3(6, 8), dim3(256), 0, stream>>>(env, Wq, Wk, Wv, bq, bk, bv, envq);
  k_gemm<<<dim3(1536), dim3(256), 0, stream>>>(xbb, Wt, envq, gate, qb, kb, vT);

  if (ws_size >= S8_OFF + 67108864UL) {
    __bf16* S8 = (__bf16*)(ws + S8_OFF);
    k_sexp<8><<<dim3(2048), dim3(256), 0, stream>>>(qb, kb, S8, lpart);
    k_lred<<<dim3(64), dim3(256), 0, stream>>>(lpart, invl);
    k_pv<8>  <<<dim3(512),  dim3(256), 0, stream>>>(S8, vT, invl, out);
  } else {
    const size_t hb = 4UL * 2048 * 512;
    const size_t hv = 4UL * 512 * 2048;
    const size_t ho = 4UL * 2048 * 512;
    k_sexp<4><<<dim3(1024), dim3(256), 0, stream>>>(qb, kb, Sbuf, lpart);
    k_lred<<<dim3(32), dim3(256), 0, stream>>>(lpart, invl);
    k_pv<4>  <<<dim3(256),  dim3(256), 0, stream>>>(Sbuf, vT, invl, out);
    k_sexp<4><<<dim3(1024), dim3(256), 0, stream>>>(qb + hb, kb + hb, Sbuf, lpart);
    k_lred<<<dim3(32), dim3(256), 0, stream>>>(lpart, invl);
    k_pv<4>  <<<dim3(256),  dim3(256), 0, stream>>>(Sbuf, vT + hv, invl, out + ho);
  }
}

// Round 16
// 162.170 us; speedup vs baseline: 1.0278x; 1.0278x over previous
//
#include <hip/hip_runtime.h>
#include <stdint.h>

typedef __attribute__((ext_vector_type(8))) __bf16 bf16x8;
typedef __attribute__((ext_vector_type(4))) __bf16 bf16x4;
typedef __attribute__((ext_vector_type(4))) float  f32x4;

#define DEV __device__ __forceinline__

DEV void gload16(const void* g, void* l) {
  __builtin_amdgcn_global_load_lds((const __attribute__((address_space(1))) uint32_t*)g,
                                   (__attribute__((address_space(3))) uint32_t*)l,
                                   16, 0, 0);
}

DEV f32x4 mfma16(bf16x8 a, bf16x8 b, f32x4 c) {
  return __builtin_amdgcn_mfma_f32_16x16x32_bf16(a, b, c, 0, 0, 0);
}

// ---------------- workspace layout (bytes) ----------------
#define XB_OFF   0UL            // xbb: 16384 x 1024 bf16 = 33,554,432 ; reused as S (group mode)
#define S_OFF    0UL            // S (4-batch group): 33,554,432
#define Q_OFF    33554432UL     // 16384 x 512 bf16 = 16,777,216
#define K_OFF    50331648UL
#define VT_OFF   67108864UL     // [8][512][2048] bf16 = 16,777,216
#define WT_OFF   83886080UL     // 1536 x 1024 bf16 = 3,145,728
#define ENVQ_OFF 87031808UL     // 8 x 1536 f32 = 49,152
#define GATE_OFF 87080960UL     // 16384 f32 = 65,536
#define S8_OFF   87146496UL     // S (all 8 batches): 67,108,864 -> needs ws >= 154,255,360

// ============ kernel 1: xbb (bf16 cast of tf) + gate ============
__global__ __launch_bounds__(256) void k_xbgate(
    const float* __restrict__ tf, const float* __restrict__ env,
    const float* __restrict__ Wg, const float* __restrict__ bg,
    __bf16* __restrict__ xbb, float* __restrict__ gate) {
  const int row = blockIdx.x;     // 0..16383
  const int t   = threadIdx.x;    // 0..255
  const int b   = row >> 11;
  const float4 v  = ((const float4*)(tf + (size_t)row * 1024))[t];
  const float4 wv = ((const float4*)Wg)[t];
  float dot = v.x * wv.x + v.y * wv.y + v.z * wv.z + v.w * wv.w;
  bf16x4 o; o.x = (__bf16)v.x; o.y = (__bf16)v.y; o.z = (__bf16)v.z; o.w = (__bf16)v.w;
  *(bf16x4*)(xbb + (size_t)row * 1024 + t * 4) = o;
  if (t < 16) {
    const float4 e  = ((const float4*)(env + b * 64))[t];
    const float4 we = ((const float4*)Wg)[256 + t];
    dot += e.x * we.x + e.y * we.y + e.z * we.z + e.w * we.w;
  }
  #pragma unroll
  for (int m = 1; m < 64; m <<= 1) dot += __shfl_xor(dot, m, 64);
  __shared__ float red[4];
  if ((t & 63) == 0) red[t >> 6] = dot;
  __syncthreads();
  if (t == 0) {
    const float d = red[0] + red[1] + red[2] + red[3] + bg[0];
    gate[row] = 0.03125f / (1.0f + __expf(-d));   // sigmoid * 1/sqrt(1024)
  }
}

// ============ kernel 2: Wt[n][kk] = W[kk][n], kk < 1024 only ============
__global__ __launch_bounds__(256) void k_wt(
    const float* __restrict__ Wq, const float* __restrict__ Wk, const float* __restrict__ Wv,
    __bf16* __restrict__ Wt) {
  __shared__ float tile[64][65];
  const int kt = blockIdx.x;       // 0..15
  const int ct = blockIdx.y;       // 0..7
  const int which = blockIdx.z;    // 0=q 1=k 2=v
  const float* W = (which == 0) ? Wq : (which == 1) ? Wk : Wv;
  const int t = threadIdx.x;
  const int k0 = kt * 64, c0 = ct * 64;
  #pragma unroll
  for (int j = 0; j < 4; ++j) {
    const int rr = (t >> 4) + j * 16;
    const float4 v4 = *(const float4*)(W + (size_t)(k0 + rr) * 512 + c0 + (t & 15) * 4);
    tile[rr][(t & 15) * 4 + 0] = v4.x;
    tile[rr][(t & 15) * 4 + 1] = v4.y;
    tile[rr][(t & 15) * 4 + 2] = v4.z;
    tile[rr][(t & 15) * 4 + 3] = v4.w;
  }
  __syncthreads();
  #pragma unroll
  for (int j = 0; j < 4; ++j) {
    const int nl = (t >> 4) + j * 16;
    const int kl = (t & 15) * 4;
    bf16x4 o;
    o.x = (__bf16)tile[kl + 0][nl];
    o.y = (__bf16)tile[kl + 1][nl];
    o.z = (__bf16)tile[kl + 2][nl];
    o.w = (__bf16)tile[kl + 3][nl];
    *(bf16x4*)(Wt + (size_t)(which * 512 + c0 + nl) * 1024 + k0 + kl) = o;
  }
}

// ============ kernel 2b: envq[b][n] = bias[n] + env[b] . W[1024:1088][col] ============
__global__ __launch_bounds__(256) void k_envq(
    const float* __restrict__ env,
    const float* __restrict__ Wq, const float* __restrict__ Wk, const float* __restrict__ Wv,
    const float* __restrict__ bq, const float* __restrict__ bk, const float* __restrict__ bv,
    float* __restrict__ envq) {
  const int n = blockIdx.x * 256 + threadIdx.x;   // 0..1535
  const int b = blockIdx.y;
  const int which = n >> 9, col = n & 511;
  const float* W    = (which == 0) ? Wq : (which == 1) ? Wk : Wv;
  const float* bias = (which == 0) ? bq : (which == 1) ? bk : bv;
  float s = bias[col];
  #pragma unroll 8
  for (int kk = 0; kk < 64; ++kk)
    s += env[b * 64 + kk] * W[(size_t)(1024 + kk) * 512 + col];
  envq[b * 1536 + n] = s;
}

// ============ kernel 3: QKV GEMM  M=16384 N=1536 K=1024 (m97 structure) ============
// v-blocks (bn>=8) add bias and write vT DIRECTLY via LDS XOR-swizzled transpose.
__global__ __launch_bounds__(256, 3) void k_gemm(
    const __bf16* __restrict__ xbb, const __bf16* __restrict__ Wt,
    const float* __restrict__ envq, const float* __restrict__ gate,
    __bf16* __restrict__ q, __bf16* __restrict__ k, __bf16* __restrict__ vT) {
  __shared__ alignas(16) __bf16 SM[16384];   // As | Bs ; reused as transpose tile
  __bf16* As = SM;
  __bf16* Bs = SM + 8192;
  const int id = blockIdx.x;
  const int xcd = id & 7, local = id >> 3;
  const int bm = xcd * 16 + (local & 15);
  const int bn = local >> 4;
  const int tid = threadIdx.x, w = tid >> 6, lane = tid & 63;
  const int g = lane >> 4, l15 = lane & 15;
  const int wm = w >> 1, wn = w & 1;
  f32x4 acc[4][4] = {};
  const char* Ab = (const char*)(xbb + (size_t)bm * 128 * 1024);
  const char* Bb = (const char*)(Wt + (size_t)bn * 128 * 1024);

  for (int kt = 0; kt < 16; ++kt) {
    const int k0b = kt * 128;
    #pragma unroll
    for (int i = 0; i < 4; ++i) {
      const int L = i * 4096 + w * 1024 + lane * 16;
      const int row = L >> 7;
      const int ch = (L >> 4) & 7;
      const int sch = ch ^ (row & 7);
      gload16(Ab + (size_t)row * 2048 + k0b + sch * 16, (char*)As + L);
      gload16(Bb + (size_t)row * 2048 + k0b + sch * 16, (char*)Bs + L);
    }
    __syncthreads();
    #pragma unroll
    for (int kk = 0; kk < 2; ++kk) {
      bf16x8 aF[4], bF[4];
      #pragma unroll
      for (int i = 0; i < 4; ++i) {
        const int rowa = wm * 64 + i * 16 + l15;
        const int cha = (kk * 4 + g) ^ (rowa & 7);
        aF[i] = *(const bf16x8*)((const char*)As + rowa * 128 + cha * 16);
        const int rowb = wn * 64 + i * 16 + l15;
        const int chb = (kk * 4 + g) ^ (rowb & 7);
        bF[i] = *(const bf16x8*)((const char*)Bs + rowb * 128 + chb * 16);
      }
      #pragma unroll
      for (int i = 0; i < 4; ++i)
        #pragma unroll
        for (int j = 0; j < 4; ++j)
          acc[i][j] = mfma16(aF[i], bF[j], acc[i][j]);
    }
    __syncthreads();
  }

  const int which = bn >> 2;          // 0=q 1=k 2=v (block-uniform)
  const int batch = bm >> 4;          // 128-row tiles never cross batch
  if (which < 2) {
    __bf16* outp = (which == 0) ? q : k;
    const int ncolbase = bn * 128 + wn * 64 - which * 512;
    #pragma unroll
    for (int i = 0; i < 4; ++i) {
      #pragma unroll
      for (int r = 0; r < 4; ++r) {
        const int mrow = bm * 128 + wm * 64 + i * 16 + g * 4 + r;
        const float gt = (which == 0) ? gate[mrow] : 1.0f;
        #pragma unroll
        for (int j = 0; j < 4; ++j) {
          const int ncol = ncolbase + j * 16 + l15;
          float val = acc[i][j][r] + envq[batch * 1536 + bn * 128 + wn * 64 + j * 16 + l15];
          if (which == 0) val *= gt;
          outp[(size_t)mrow * 512 + ncol] = (__bf16)val;
        }
      }
    }
  } else {
    // v-block: bias add + 128x128 LDS transpose (XOR swizzle, <=2-way banks) -> vT
    #pragma unroll
    for (int j = 0; j < 4; ++j) {
      const int ncol = wn * 64 + j * 16 + l15;                 // local dim 0..127
      const float bv = envq[batch * 1536 + bn * 128 + ncol];
      const int sw = (ncol & 7) << 3;
      #pragma unroll
      for (int i = 0; i < 4; ++i) {
        const int mbase = wm * 64 + i * 16 + g * 4;            // local key, 4-aligned
        bf16x4 pk;
        pk.x = (__bf16)(acc[i][j][0] + bv);
        pk.y = (__bf16)(acc[i][j][1] + bv);
        pk.z = (__bf16)(acc[i][j][2] + bv);
        pk.w = (__bf16)(acc[i][j][3] + bv);
        *(bf16x4*)(SM + ncol * 128 + (mbase ^ sw)) = pk;
      }
    }
    __syncthreads();
    const int colL = tid & 127, h = tid >> 7;
    const __bf16* src = SM + colL * 128;
    const int sw = (colL & 7) << 3;
    __bf16* dst = vT + ((size_t)batch * 512 + (bn - 8) * 128 + colL) * 2048
                     + (bm & 15) * 128 + h * 64;
    #pragma unroll
    for (int c = 0; c < 8; ++c) {
      const int m0 = h * 64 + c * 8;
      *(bf16x8*)(dst + c * 8) = *(const bf16x8*)(src + (m0 ^ sw));
    }
  }
}

// ============ kernel 5: S = exp(Q @ K^T), m97 128^2, NB batches ============
template<int NB>
__global__ __launch_bounds__(256, 3) void k_sexp(
    const __bf16* __restrict__ q, const __bf16* __restrict__ kg,
    __bf16* __restrict__ S) {
  __shared__ alignas(16) __bf16 As[8192];
  __shared__ alignas(16) __bf16 Bs[8192];
  const int id = blockIdx.x;
  int batch, t;
  if (NB == 8) { batch = id & 7;        t = id >> 3; }
  else         { batch = (id & 7) >> 1; t = ((id >> 3) << 1) | (id & 1); }
  const int mt = t & 15, nt = t >> 4;
  const int tid = threadIdx.x, w = tid >> 6, lane = tid & 63;
  const int g = lane >> 4, l15 = lane & 15;
  const int wm = w >> 1, wn = w & 1;
  f32x4 acc[4][4] = {};
  const char* Ab = (const char*)(q  + ((size_t)batch * 2048 + mt * 128) * 512);
  const char* Bb = (const char*)(kg + ((size_t)batch * 2048 + nt * 128) * 512);

  for (int kt = 0; kt < 8; ++kt) {
    const int k0b = kt * 128;
    #pragma unroll
    for (int i = 0; i < 4; ++i) {
      const int L = i * 4096 + w * 1024 + lane * 16;
      const int row = L >> 7;
      const int ch = (L >> 4) & 7;
      const int sch = ch ^ (row & 7);
      gload16(Ab + (size_t)row * 1024 + k0b + sch * 16, (char*)As + L);
      gload16(Bb + (size_t)row * 1024 + k0b + sch * 16, (char*)Bs + L);
    }
    __syncthreads();
    #pragma unroll
    for (int kk = 0; kk < 2; ++kk) {
      bf16x8 aF[4], bF[4];
      #pragma unroll
      for (int i = 0; i < 4; ++i) {
        const int rowa = wm * 64 + i * 16 + l15;
        const int cha = (kk * 4 + g) ^ (rowa & 7);
        aF[i] = *(const bf16x8*)((const char*)As + rowa * 128 + cha * 16);
        const int rowb = wn * 64 + i * 16 + l15;
        const int chb = (kk * 4 + g) ^ (rowb & 7);
        bF[i] = *(const bf16x8*)((const char*)Bs + rowb * 128 + chb * 16);
      }
      #pragma unroll
      for (int i = 0; i < 4; ++i)
        #pragma unroll
        for (int j = 0; j < 4; ++j)
          acc[i][j] = mfma16(aF[i], bF[j], acc[i][j]);
    }
    __syncthreads();
  }

  __bf16* Srow = S + (size_t)batch * 2048 * 2048;
  #pragma unroll
  for (int i = 0; i < 4; ++i) {
    #pragma unroll
    for (int r = 0; r < 4; ++r) {
      const int mrow = mt * 128 + wm * 64 + i * 16 + g * 4 + r;
      #pragma unroll
      for (int j = 0; j < 4; ++j) {
        const int ncol = nt * 128 + wn * 64 + j * 16 + l15;
        Srow[(size_t)mrow * 2048 + ncol] = (__bf16)__expf(acc[i][j][r]);
      }
    }
  }
}

// ============ kernel 6: out = (S @ vT-rows) / (S @ 1), m97 128^2 tile ============
// nt-blocks of one S panel are ADJACENT in id (mt = h>>2, nt = h&3) -> co-resident
// on the same XCD at the same time -> S panel fetched ~once, nt>=1 reads hit L2.
template<int NB>
__global__ __launch_bounds__(256, 3) void k_pv(
    const __bf16* __restrict__ S, const __bf16* __restrict__ vT,
    float* __restrict__ out) {
  __shared__ alignas(16) __bf16 As[8192];
  __shared__ alignas(16) __bf16 Bs[8192];
  const int id = blockIdx.x;
  int batch, mt, nt;
  if (NB == 8) { batch = id & 7; const int h = id >> 3; mt = h >> 2; nt = h & 3; }
  else { batch = (id & 7) >> 1; const int h = ((id >> 3) << 1) | (id & 1); mt = h >> 2; nt = h & 3; }
  const int tid = threadIdx.x, w = tid >> 6, lane = tid & 63;
  const int g = lane >> 4, l15 = lane & 15;
  const int wm = w >> 1, wn = w & 1;
  f32x4 acc[4][4] = {};
  f32x4 l_acc[4] = {};
  bf16x8 ones;
  #pragma unroll
  for (int j = 0; j < 8; ++j) ones[j] = (__bf16)1.0f;

  const char* Ab = (const char*)(S  + ((size_t)batch * 2048 + mt * 128) * 2048);
  const char* Bb = (const char*)(vT + ((size_t)batch * 512 + nt * 128) * 2048);

  for (int kt = 0; kt < 32; ++kt) {
    const int k0b = kt * 128;
    #pragma unroll
    for (int i = 0; i < 4; ++i) {
      const int L = i * 4096 + w * 1024 + lane * 16;
      const int row = L >> 7, ch = (L >> 4) & 7, sch = ch ^ (row & 7);
      gload16(Ab + (size_t)row * 4096 + k0b + sch * 16, (char*)As + L);
      gload16(Bb + (size_t)row * 4096 + k0b + sch * 16, (char*)Bs + L);
    }
    __syncthreads();
    #pragma unroll
    for (int kk = 0; kk < 2; ++kk) {
      bf16x8 aF[4], bF[4];
      #pragma unroll
      for (int i = 0; i < 4; ++i) {
        const int rowa = wm * 64 + i * 16 + l15;
        const int cha = (kk * 4 + g) ^ (rowa & 7);
        aF[i] = *(const bf16x8*)((const char*)As + rowa * 128 + cha * 16);
        const int rowb = wn * 64 + i * 16 + l15;
        const int chb = (kk * 4 + g) ^ (rowb & 7);
        bF[i] = *(const bf16x8*)((const char*)Bs + rowb * 128 + chb * 16);
      }
      #pragma unroll
      for (int i = 0; i < 4; ++i) {
        #pragma unroll
        for (int j = 0; j < 4; ++j)
          acc[i][j] = mfma16(aF[i], bF[j], acc[i][j]);
        l_acc[i] = mfma16(aF[i], ones, l_acc[i]);
      }
    }
    __syncthreads();
  }

  #pragma unroll
  for (int i = 0; i < 4; ++i) {
    #pragma unroll
    for (int r = 0; r < 4; ++r) {
      const size_t mrow = (size_t)batch * 2048 + mt * 128 + wm * 64 + i * 16 + g * 4 + r;
      const float inv = 1.0f / l_acc[i][r];
      #pragma unroll
      for (int j = 0; j < 4; ++j) {
        const int ncol = nt * 128 + wn * 64 + j * 16 + l15;
        out[mrow * 512 + ncol] = acc[i][j][r] * inv;
      }
    }
  }
}

// ============ launcher ============
extern "C" void kernel_launch(void* const* d_in, const int* in_sizes, int n_in,
                              void* d_out, int out_size, void* d_ws, size_t ws_size,
                              hipStream_t stream) {
  const float* tf  = (const float*)d_in[0];
  const float* env = (const float*)d_in[1];
  const float* Wq  = (const float*)d_in[2];
  const float* bq  = (const float*)d_in[3];
  const float* Wk  = (const float*)d_in[4];
  const float* bk  = (const float*)d_in[5];
  const float* Wv  = (const float*)d_in[6];
  const float* bv  = (const float*)d_in[7];
  const float* Wg  = (const float*)d_in[8];
  const float* bg  = (const float*)d_in[9];
  float* out = (float*)d_out;
  char* ws = (char*)d_ws;

  __bf16* xbb  = (__bf16*)(ws + XB_OFF);
  __bf16* Sbuf = (__bf16*)(ws + S_OFF);
  __bf16* qb   = (__bf16*)(ws + Q_OFF);
  __bf16* kb   = (__bf16*)(ws + K_OFF);
  __bf16* vT   = (__bf16*)(ws + VT_OFF);
  __bf16* Wt   = (__bf16*)(ws + WT_OFF);
  float* envq  = (float*)(ws + ENVQ_OFF);
  float* gate  = (float*)(ws + GATE_OFF);

  k_xbgate<<<dim3(16384), dim3(256), 0, stream>>>(tf, env, Wg, bg, xbb, gate);
  k_wt<<<dim3(16, 8, 3), dim3(256), 0, stream>>>(Wq, Wk, Wv, Wt);
  k_envq<<<dim3(6, 8), dim3(256), 0, stream>>>(env, Wq, Wk, Wv, bq, bk, bv, envq);
  k_gemm<<<dim3(1536), dim3(256), 0, stream>>>(xbb, Wt, envq, gate, qb, kb, vT);

  if (ws_size >= S8_OFF + 67108864UL) {
    __bf16* S8 = (__bf16*)(ws + S8_OFF);
    k_sexp<8><<<dim3(2048), dim3(256), 0, stream>>>(qb, kb, S8);
    k_pv<8>  <<<dim3(512),  dim3(256), 0, stream>>>(S8, vT, out);
  } else {
    const size_t hb = 4UL * 2048 * 512;
    const size_t hv = 4UL * 512 * 2048;
    const size_t ho = 4UL * 2048 * 512;
    k_sexp<4><<<dim3(1024), dim3(256), 0, stream>>>(qb, kb, Sbuf);
    k_pv<4>  <<<dim3(256),  dim3(256), 0, stream>>>(Sbuf, vT, out);
    k_sexp<4><<<dim3(1024), dim3(256), 0, stream>>>(qb + hb, kb + hb, Sbuf);
    k_pv<4>  <<<dim3(256),  dim3(256), 0, stream>>>(Sbuf, vT + hv, out + ho);
  }
}